// Round 8
// baseline (243.588 us; speedup 1.0000x reference)
//
#include <hip/hip_runtime.h>

#define IN_DIM 128
#define HC 256
#define HEADS 8
#define OUT_DIM 32
#define NEG_SLOPE 0.2f

typedef unsigned short ushort_t;
typedef unsigned int uint_t;
typedef __attribute__((ext_vector_type(8))) short bf16x8;
typedef __attribute__((ext_vector_type(4))) float floatx4;

__device__ inline ushort_t f2bf(float f) {
    uint_t u = __float_as_uint(f);
    u = (u + 0x7FFF + ((u >> 16) & 1)) >> 16;   // RNE
    return (ushort_t)u;
}
__device__ inline float bf2f(ushort_t u) {
    return __uint_as_float(((uint_t)u) << 16);
}

// ---------------- K0: pack W into B-fragment bf16 layout + zero deg ----------------
__global__ __launch_bounds__(256) void prep_w(const float* __restrict__ W,
                                              ushort_t* __restrict__ Wf,
                                              int* __restrict__ deg, int N) {
    int t = blockIdx.x * 256 + threadIdx.x;      // 0..4095
    int lane = t & 63;
    int ks = (t >> 6) & 3;
    int nt = t >> 8;
    int n = nt * 16 + (lane & 15);
    int k0 = ks * 32 + (lane >> 4) * 8;
    ushort_t v[8];
#pragma unroll
    for (int j = 0; j < 8; j++) v[j] = f2bf(W[(size_t)(k0 + j) * HC + n]);
    uint4 pk;
    pk.x = v[0] | ((uint_t)v[1] << 16);
    pk.y = v[2] | ((uint_t)v[3] << 16);
    pk.z = v[4] | ((uint_t)v[5] << 16);
    pk.w = v[6] | ((uint_t)v[7] << 16);
    *(uint4*)&Wf[(size_t)t * 8] = pk;
    for (int i = t; i < N; i += 4096) deg[i] = 0;
}

// ---------------- K1: h2 = bf16(x @ W) via MFMA, fused a_src/a_dst epilogue ----------------
__global__ __launch_bounds__(256) void gemm_mfma(const float* __restrict__ x,
                                                 const ushort_t* __restrict__ Wf,
                                                 const float* __restrict__ att_s,
                                                 const float* __restrict__ att_d,
                                                 ushort_t* __restrict__ h2,
                                                 float* __restrict__ a_src,
                                                 float* __restrict__ a_dst, int N) {
    __shared__ ushort_t xs[128 * 136];
    const int tid = threadIdx.x;
    const int row0 = blockIdx.x * 128;
#pragma unroll
    for (int i = 0; i < 16; i++) {
        int slot = tid + i * 256;                // 4096 float4-slots
        int r = slot >> 5, kq = slot & 31;
        int gr = row0 + r;
        float4 v = (gr < N) ? *(const float4*)&x[(size_t)gr * IN_DIM + kq * 4]
                            : make_float4(0.f, 0.f, 0.f, 0.f);
        uint2 pk;
        pk.x = f2bf(v.x) | ((uint_t)f2bf(v.y) << 16);
        pk.y = f2bf(v.z) | ((uint_t)f2bf(v.w) << 16);
        *(uint2*)&xs[r * 136 + kq * 4] = pk;
    }
    __syncthreads();

    const int lane = tid & 63;
    const int w = tid >> 6;
    const int wm = (w & 1) * 64;
    const int colblk = blockIdx.y * 128 + (w >> 1) * 64;
    const int m15 = lane & 15, quad = lane >> 4;

    floatx4 acc[4][4] = {};
#pragma unroll
    for (int ks = 0; ks < 4; ks++) {
        bf16x8 a[4], b[4];
#pragma unroll
        for (int mt = 0; mt < 4; mt++)
            a[mt] = *(const bf16x8*)&xs[(wm + mt * 16 + m15) * 136 + ks * 32 + quad * 8];
#pragma unroll
        for (int nt = 0; nt < 4; nt++) {
            int ntg = (colblk >> 4) + nt;
            b[nt] = *(const bf16x8*)&Wf[(size_t)(((ntg * 4 + ks) * 64) + lane) * 8];
        }
#pragma unroll
        for (int mt = 0; mt < 4; mt++)
#pragma unroll
            for (int nt = 0; nt < 4; nt++)
                acc[mt][nt] = __builtin_amdgcn_mfma_f32_16x16x32_bf16(a[mt], b[nt], acc[mt][nt], 0, 0, 0);
    }

    // epilogue: C layout col=lane&15, row=(lane>>4)*4+reg  [m89]
    const int cbase = colblk + m15;
    const int head0 = colblk >> 5;               // 64 cols = 2 heads
    float as0 = att_s[colblk + m15],      as1 = att_s[colblk + 16 + m15];
    float as2 = att_s[colblk + 32 + m15], as3 = att_s[colblk + 48 + m15];
    float ad0 = att_d[colblk + m15],      ad1 = att_d[colblk + 16 + m15];
    float ad2 = att_d[colblk + 32 + m15], ad3 = att_d[colblk + 48 + m15];
#pragma unroll
    for (int mt = 0; mt < 4; mt++) {
#pragma unroll
        for (int reg = 0; reg < 4; reg++) {
            int gr = row0 + wm + mt * 16 + quad * 4 + reg;
            float sA = acc[mt][0][reg] * as0 + acc[mt][1][reg] * as1;
            float sB = acc[mt][2][reg] * as2 + acc[mt][3][reg] * as3;
            float dA = acc[mt][0][reg] * ad0 + acc[mt][1][reg] * ad1;
            float dB = acc[mt][2][reg] * ad2 + acc[mt][3][reg] * ad3;
#pragma unroll
            for (int off = 1; off < 16; off <<= 1) {
                sA += __shfl_xor(sA, off, 64);
                sB += __shfl_xor(sB, off, 64);
                dA += __shfl_xor(dA, off, 64);
                dB += __shfl_xor(dB, off, 64);
            }
            if (gr < N) {
#pragma unroll
                for (int nt = 0; nt < 4; nt++)
                    h2[(size_t)gr * HC + cbase + nt * 16] = f2bf(acc[mt][nt][reg]);
                if (m15 == 0) {
                    a_src[gr * HEADS + head0] = sA;
                    a_src[gr * HEADS + head0 + 1] = sB;
                    a_dst[gr * HEADS + head0] = dA;
                    a_dst[gr * HEADS + head0 + 1] = dB;
                }
            }
        }
    }
}

// ---------------- K2: count + per-edge rank (standalone, high occupancy) ----------------
__global__ void count_rank(const int* __restrict__ dst, int* __restrict__ deg,
                           ushort_t* __restrict__ rank, int E) {
    int i = blockIdx.x * 256 + threadIdx.x;
    int base = i * 4;
    if (base + 3 < E) {
        int4 d = *(const int4*)&dst[base];
        rank[base + 0] = (ushort_t)atomicAdd(&deg[d.x], 1);
        rank[base + 1] = (ushort_t)atomicAdd(&deg[d.y], 1);
        rank[base + 2] = (ushort_t)atomicAdd(&deg[d.z], 1);
        rank[base + 3] = (ushort_t)atomicAdd(&deg[d.w], 1);
    } else {
        for (int j = base; j < E; j++) rank[j] = (ushort_t)atomicAdd(&deg[dst[j]], 1);
    }
}

// ---------------- scan ----------------
__global__ __launch_bounds__(1024) void scan_pass1(const int* __restrict__ deg,
                                                   int* __restrict__ rs,
                                                   int* __restrict__ bsum, int N) {
    __shared__ int wsum[16], wexcl[16];
    int tid = threadIdx.x, lane = tid & 63, w = tid >> 6;
    int base = blockIdx.x * 4096 + tid * 4;
    int v[4];
#pragma unroll
    for (int j = 0; j < 4; j++) v[j] = (base + j < N) ? deg[base + j] : 0;
    int s = v[0] + v[1] + v[2] + v[3];
    int xsc = s;
#pragma unroll
    for (int off = 1; off < 64; off <<= 1) {
        int t = __shfl_up(xsc, off, 64);
        if (lane >= off) xsc += t;
    }
    if (lane == 63) wsum[w] = xsc;
    __syncthreads();
    if (w == 0 && lane < 16) {
        int y = wsum[lane], z = y;
#pragma unroll
        for (int off = 1; off < 16; off <<= 1) {
            int t = __shfl_up(z, off, 64);
            if (lane >= off) z += t;
        }
        wexcl[lane] = z - y;
        if (lane == 15) bsum[blockIdx.x] = z;
    }
    __syncthreads();
    int e = wexcl[w] + (xsc - s);
#pragma unroll
    for (int j = 0; j < 4; j++) {
        if (base + j < N) rs[base + j] = e;
        e += v[j];
    }
}

__global__ __launch_bounds__(256) void scan_pass23(int* __restrict__ rs,
                                                   const int* __restrict__ bsum,
                                                   int N, int nb) {
    __shared__ int soff, stot;
    int tid = threadIdx.x;
    if (tid < 64) {
        int v = (tid < nb) ? bsum[tid] : 0;
        int incl = v;
#pragma unroll
        for (int off = 1; off < 64; off <<= 1) {
            int t = __shfl_up(incl, off, 64);
            if (tid >= off) incl += t;
        }
        int chunk = blockIdx.x >> 4;             // 16 blocks per 4096-chunk
        int off_ = __shfl(incl - v, chunk, 64);
        int tot_ = __shfl(incl, nb - 1, 64);
        if (tid == 0) { soff = off_; stot = tot_; }
    }
    __syncthreads();
    int i = blockIdx.x * 256 + tid;
    if (i < N) rs[i] += soff;
    if (i == N) rs[N] = stot;
}

__global__ void scatter_edges(const int* __restrict__ src, const int* __restrict__ dst,
                              const ushort_t* __restrict__ rank,
                              const int* __restrict__ row_start,
                              ushort_t* __restrict__ csr_src, int E) {
    int i = blockIdx.x * 256 + threadIdx.x;
    int base = i * 4;
    if (base + 3 < E) {
        int4 s = *(const int4*)&src[base];
        int4 d = *(const int4*)&dst[base];
        ushort4 r = *(const ushort4*)&rank[base];
        csr_src[row_start[d.x] + r.x] = (ushort_t)s.x;
        csr_src[row_start[d.y] + r.y] = (ushort_t)s.y;
        csr_src[row_start[d.z] + r.z] = (ushort_t)s.z;
        csr_src[row_start[d.w] + r.w] = (ushort_t)s.w;
    } else {
        for (int j = base; j < E; j++)
            csr_src[row_start[dst[j]] + rank[j]] = (ushort_t)src[j];
    }
}

// ---------------- aggregate: one wave per node, predicated batch-8 (no scalar tail) ----------------
__global__ __launch_bounds__(512) void aggregate(const ushort_t* __restrict__ h2,
                                                 const float* __restrict__ a_src,
                                                 const float* __restrict__ a_dst,
                                                 const int* __restrict__ row_start,
                                                 const ushort_t* __restrict__ csr_src,
                                                 const float* __restrict__ bias,
                                                 float* __restrict__ out, int N) {
    int wave = threadIdx.x >> 6;
    int lane = threadIdx.x & 63;
    int n = blockIdx.x * 8 + wave;
    if (n >= N) return;
    int head = lane >> 3;
    int coff = head * OUT_DIM + (lane & 7) * 4;

    float adst = a_dst[n * HEADS + head];
    float e = a_src[n * HEADS + head] + adst;
    e = fmaxf(e, NEG_SLOPE * e);
    float p = __expf(e);
    ushort4 hv = *(const ushort4*)&h2[(size_t)n * HC + coff];
    float ax = p * bf2f(hv.x), ay = p * bf2f(hv.y), az = p * bf2f(hv.z), aw = p * bf2f(hv.w);
    float l = p;

    int kb = __builtin_amdgcn_readfirstlane(row_start[n]);
    int ke = __builtin_amdgcn_readfirstlane(row_start[n + 1]);
    for (int k = kb; k < ke; k += 8) {
        int sidx[8];
        ushort4 g[8];
        float ev[8];
#pragma unroll
        for (int j = 0; j < 8; j++) {
            int kk = k + j;
            int kc = (kk < ke) ? kk : (ke - 1);          // clamp tail to last edge
            sidx[j] = __builtin_amdgcn_readfirstlane((int)csr_src[kc]);
        }
#pragma unroll
        for (int j = 0; j < 8; j++) {
            g[j] = *(const ushort4*)&h2[(size_t)sidx[j] * HC + coff];
            ev[j] = a_src[sidx[j] * HEADS + head];
        }
#pragma unroll
        for (int j = 0; j < 8; j++) {
            float ej = ev[j] + adst;
            ej = fmaxf(ej, NEG_SLOPE * ej);
            float pj = (k + j < ke) ? __expf(ej) : 0.f;  // mask clamped slots
            ax += pj * bf2f(g[j].x);
            ay += pj * bf2f(g[j].y);
            az += pj * bf2f(g[j].z);
            aw += pj * bf2f(g[j].w);
            l += pj;
        }
    }

    float inv = 1.f / l;
    float rx = ax * inv, ry = ay * inv, rz = az * inv, rw = aw * inv;
#pragma unroll
    for (int off = 8; off < 64; off <<= 1) {
        rx += __shfl_xor(rx, off, 64);
        ry += __shfl_xor(ry, off, 64);
        rz += __shfl_xor(rz, off, 64);
        rw += __shfl_xor(rw, off, 64);
    }
    if (head == 0) {
        int c4 = (lane & 7) * 4;
        float4 b = *(const float4*)&bias[c4];
        float4 o = make_float4(0.125f * rx + b.x, 0.125f * ry + b.y,
                               0.125f * rz + b.z, 0.125f * rw + b.w);
        *(float4*)&out[(size_t)n * OUT_DIM + c4] = o;
    }
}

// ---------------- launch ----------------
extern "C" void kernel_launch(void* const* d_in, const int* in_sizes, int n_in,
                              void* d_out, int out_size, void* d_ws, size_t ws_size,
                              hipStream_t stream) {
    const float* x       = (const float*)d_in[0];
    const int*   eidx    = (const int*)d_in[1];
    const float* W       = (const float*)d_in[3];
    const float* att_src = (const float*)d_in[4];
    const float* att_dst = (const float*)d_in[5];
    const float* bias    = (const float*)d_in[6];
    float* out = (float*)d_out;

    const int N = in_sizes[0] / IN_DIM;
    const int E = in_sizes[1] / 2;
    const int* esrc = eidx;
    const int* edst = eidx + E;

    char* wsb = (char*)d_ws;
    size_t off = 0;
    auto alloc = [&](size_t bytes) -> void* {
        void* p = wsb + off;
        off = (off + bytes + 255) & ~(size_t)255;
        return p;
    };
    ushort_t* h2       = (ushort_t*)alloc((size_t)N * HC * 2);
    ushort_t* Wf       = (ushort_t*)alloc((size_t)IN_DIM * HC * 2);
    float*    a_src    = (float*)alloc((size_t)N * HEADS * 4);
    float*    a_dst    = (float*)alloc((size_t)N * HEADS * 4);
    int*      deg      = (int*)alloc((size_t)N * 4);
    int*      row_start= (int*)alloc((size_t)(N + 1) * 4);
    ushort_t* rank     = (ushort_t*)alloc((size_t)E * 2);
    ushort_t* csr_src  = (ushort_t*)alloc((size_t)E * 2);
    const int nb = (N + 4095) / 4096;
    int*      bsum     = (int*)alloc((size_t)(nb + 1) * 4);

    hipLaunchKernelGGL(prep_w, dim3(16), dim3(256), 0, stream, W, Wf, deg, N);
    hipLaunchKernelGGL(gemm_mfma, dim3((N + 127) / 128, 2), dim3(256), 0, stream,
                       x, Wf, att_src, att_dst, h2, a_src, a_dst, N);
    hipLaunchKernelGGL(count_rank, dim3((E / 4 + 255) / 256), dim3(256), 0, stream,
                       edst, deg, rank, E);
    hipLaunchKernelGGL(scan_pass1, dim3(nb), dim3(1024), 0, stream, deg, row_start, bsum, N);
    hipLaunchKernelGGL(scan_pass23, dim3((N + 256) / 256), dim3(256), 0, stream,
                       row_start, bsum, N, nb);
    hipLaunchKernelGGL(scatter_edges, dim3((E / 4 + 255) / 256), dim3(256), 0, stream,
                       esrc, edst, rank, row_start, csr_src, E);
    hipLaunchKernelGGL(aggregate, dim3((N + 7) / 8), dim3(512), 0, stream,
                       h2, a_src, a_dst, row_start, csr_src, bias, out, N);
}